// Round 4
// baseline (2957.798 us; speedup 1.0000x reference)
//
#include <hip/hip_runtime.h>
#include <cstdint>
#include <cstddef>

#define N_NODES 100000
#define N_EDGES 1600000
// n_in = n_out = 32; edge MLP: 96 -> 96 -> 129; out MLPs: 160 -> 32

// ================= fallback (atomic) workspace layout — element offsets =====
#define O_S1   0u
#define O_M4S  3200000u
#define O_M2K  6400000u
#define O_DEG  9600000u
#define O_M3K  9700000u
#define O_WC   12900000u
#define O_C0   12903072u
#define WS_ELEMS 12903104u
#define WS_BYTES ((size_t)WS_ELEMS * 4u)

// ================= CSR workspace layout (WS2: round-1/3 path) ===============
#define O2_DEG   0u          // uint  [N_NODES]      in-degree (init 0)
#define O2_OFF   100000u     // uint  [N_NODES+1]    CSR exclusive offsets
#define O2_CUR   200004u     // uint  [N_NODES]      fill cursors
#define O2_EIDX  300004u     // uint  [N_EDGES]      edge ids grouped by dst
#define O2_WC    1900004u    // float [96*32]        Wm2[:,1:] @ We[0:128]
#define O2_C0    1903076u    // float [32]           bm2[1:]  @ We[0:128]
#define O2_F     1903108u    // float [N_EDGES*128]  gated messages f
#define WS2_ELEMS (1903108u + 204800000u)
#define WS2_BYTES ((size_t)WS2_ELEMS * 4u)

// ====== WS3: adds h + gate for the split LDS-weight edge pipeline ===========
// Round-3 diagnosis: edge kernel stalls ~70% on SGPR weight streaming (SGPR
// file 112 regs vs 140KB/wave weight stream; sL1 16KB << Wm2 49.5KB). Fix:
// LDS-resident weights (ds_read broadcast, deeply pipelined) + 4 threads per
// edge so per-thread register state stays ~50-120 VGPR (no h[96]xf[32]
// tension -> no spill).
#define O2_H   206703108u    // float [N_EDGES*96]   relu'd hidden h (16B-aligned)
#define O2_G   360303108u    // float [N_EDGES]      sigmoid gate
#define WS3_ELEMS 361903108u
#define WS3_BYTES ((size_t)WS3_ELEMS * 4u)

// order-preserving float<->uint key (fallback path)
__device__ __forceinline__ unsigned fkey(float v){
  unsigned b = __float_as_uint(v);
  return (b & 0x80000000u) ? ~b : (b | 0x80000000u);
}
__device__ __forceinline__ float fdec(unsigned u){
  unsigned b = (u & 0x80000000u) ? (u & 0x7fffffffu) : ~u;
  return __uint_as_float(b);
}

template<int NJ>
__device__ __forceinline__ void accN(float xv, const float* w, float* acc){
  #pragma unroll
  for (int j = 0; j < NJ; j++) acc[j] = fmaf(xv, w[j], acc[j]);
}

// ---- precompute Wc = Wm2[:,1:129] @ We[0:128,:]  and  c0 = bm2[1:129] @ We ----
__global__ __launch_bounds__(256) void gsmp_make_wc(
    const float* __restrict__ Wm2, const float* __restrict__ bm2,
    const float* __restrict__ We, float* __restrict__ Wc, float* __restrict__ c0)
{
  int t = blockIdx.x * 256 + threadIdx.x;
  if (t < 96 * 32) {
    int k = t >> 5, j = t & 31;
    float s = 0.f;
    for (int i = 0; i < 128; i++) s = fmaf(Wm2[k * 129 + 1 + i], We[i * 32 + j], s);
    Wc[t] = s;
  } else if (t < 96 * 32 + 32) {
    int j = t - 96 * 32;
    float s = 0.f;
    for (int i = 0; i < 128; i++) s = fmaf(bm2[1 + i], We[i * 32 + j], s);
    c0[j] = s;
  }
}

// ============================ CSR build =====================================
__global__ __launch_bounds__(256) void gsmp_hist(
    const int* __restrict__ dst, unsigned* __restrict__ deg)
{
  int e = blockIdx.x * 256 + threadIdx.x;
  if (e < N_EDGES) atomicAdd(&deg[dst[e]], 1u);
}

__global__ __launch_bounds__(1024) void gsmp_scan(float* __restrict__ wsf)
{
  unsigned* deg = (unsigned*)wsf + O2_DEG;
  unsigned* off = (unsigned*)wsf + O2_OFF;
  unsigned* cur = (unsigned*)wsf + O2_CUR;
  __shared__ unsigned wsum[16];
  __shared__ unsigned carry_s, total_s;
  int t = threadIdx.x;
  int w = t >> 6, lane = t & 63;
  if (t == 0) carry_s = 0u;
  __syncthreads();
  for (int base = 0; base < N_NODES; base += 1024) {
    int n = base + t;
    unsigned v = (n < N_NODES) ? deg[n] : 0u;
    unsigned incl = v;
    #pragma unroll
    for (int o = 1; o < 64; o <<= 1) {
      unsigned u = __shfl_up(incl, o, 64);
      if (lane >= o) incl += u;
    }
    if (lane == 63) wsum[w] = incl;
    __syncthreads();
    if (t < 16) {
      unsigned x = wsum[t], inc = x;
      #pragma unroll
      for (int o = 1; o < 16; o <<= 1) {
        unsigned u = __shfl_up(inc, o, 16);
        if (t >= o) inc += u;
      }
      wsum[t] = inc - x;
      if (t == 15) total_s = inc;
    }
    __syncthreads();
    if (n < N_NODES) {
      unsigned exc = carry_s + wsum[w] + incl - v;
      off[n] = exc;
      cur[n] = exc;
    }
    __syncthreads();
    if (t == 0) carry_s += total_s;
    __syncthreads();
  }
  if (t == 0) off[N_NODES] = carry_s;
}

__global__ __launch_bounds__(256) void gsmp_fill(
    const int* __restrict__ dst, float* __restrict__ wsf)
{
  unsigned* cur  = (unsigned*)wsf + O2_CUR;
  unsigned* eidx = (unsigned*)wsf + O2_EIDX;
  int e = blockIdx.x * 256 + threadIdx.x;
  if (e < N_EDGES) {
    unsigned pos = atomicAdd(&cur[dst[e]], 1u);
    eidx[pos] = (unsigned)e;
  }
}

// ====== kernel A: h + gate, 4 threads/edge, Wm1 LDS-resident ================
// Thread (eg,q): q owns h[24q:24q+24). Weight ds_read addrs per quad start at
// dword offsets {0,24,48,72} -> banks {0,24,16,8} (disjoint b128 bank-quads),
// 16B-aligned. 37.6KB LDS -> 4 blocks/CU possible; VGPR ~50 live.
__global__ __launch_bounds__(512, 4) void gsmp_edge_h(
    const float* __restrict__ in_vc, const float* __restrict__ in_ve,
    const int* __restrict__ src, const int* __restrict__ dst,
    const float* __restrict__ Wm1, const float* __restrict__ bm1,
    const float* __restrict__ Wm2, const float* __restrict__ bm2,
    float* __restrict__ ws)
{
  __shared__ float wlds[96 * 96];
  __shared__ float col0[96];
  __shared__ float b1[96];
  int tid = threadIdx.x;
  for (int i = tid; i < 96 * 96; i += 512) wlds[i] = Wm1[i];
  if (tid < 96) { col0[tid] = Wm2[tid * 129]; b1[tid] = bm1[tid]; }
  __syncthreads();

  int eg = tid >> 2, q = tid & 3;
  int e = blockIdx.x * 128 + eg;           // N_EDGES % 128 == 0, no tail
  int s32 = src[e] * 32, d32 = dst[e] * 32;
  size_t eoff = (size_t)e * 32;

  float h[24];
  #pragma unroll
  for (int j = 0; j < 24; j++) h[j] = b1[24 * q + j];

  const float* seg0 = in_vc + s32;
  const float* seg1 = in_vc + d32;
  const float* seg2 = in_ve + eoff;
  #pragma unroll
  for (int c = 0; c < 6; c++) {
    const float* bp = (c < 2) ? seg0 : (c < 4) ? seg1 : seg2;
    const float4* p4 = (const float4*)bp + (c & 1) * 4;
    float4 x0 = p4[0], x1 = p4[1], x2 = p4[2], x3 = p4[3];
    float xs[16] = {x0.x, x0.y, x0.z, x0.w, x1.x, x1.y, x1.z, x1.w,
                    x2.x, x2.y, x2.z, x2.w, x3.x, x3.y, x3.z, x3.w};
    int kb = c * 16;
    #pragma unroll
    for (int kk = 0; kk < 16; kk++) {
      const float* w = wlds + (kb + kk) * 96 + 24 * q;
      accN<24>(xs[kk], w, h);
    }
  }

  // relu + per-q gate partial, then 4-lane xor reduce (quad = lanes 4eg+q)
  float y = 0.f;
  #pragma unroll
  for (int j = 0; j < 24; j++) {
    h[j] = fmaxf(h[j], 0.f);
    y = fmaf(h[j], col0[24 * q + j], y);
  }
  y += __shfl_xor(y, 1, 64);
  y += __shfl_xor(y, 2, 64);
  y += bm2[0];
  float gate = 1.f / (1.f + __expf(-y));

  float* hp = ws + O2_H + (size_t)e * 96 + 24 * q;   // 96B offset: 16B-aligned
  #pragma unroll
  for (int jc = 0; jc < 6; jc++) {
    float4 o;
    o.x = h[jc * 4 + 0]; o.y = h[jc * 4 + 1];
    o.z = h[jc * 4 + 2]; o.w = h[jc * 4 + 3];
    ((float4*)hp)[jc] = o;
  }
  if (q == 0) ws[O2_G + e] = gate;
}

// ====== kernel B: f + out_ve, 4 threads/edge, Wm2'/Wc/WeT LDS-resident ======
// q owns f[32q:32q+32) (f-phase) then out_ve[8q:8q+8) (ove-phase, no reduce).
// Wm2' rows padded to 144 dwords with q-slices at q*36 -> quad bank starts
// {0,4,8,12}, 16B-aligned; Wc/WeT j-slices at 8q -> banks {0,8,16,24}.
__global__ __launch_bounds__(512, 4) void gsmp_edge_f(
    const float* __restrict__ in_ve,
    const float* __restrict__ Wm2, const float* __restrict__ bm2,
    const float* __restrict__ We, const float* __restrict__ be,
    float* __restrict__ ws, float* __restrict__ out_ve)
{
  __shared__ float wlds[96 * 144];
  __shared__ float wc[96 * 32];
  __shared__ float wet[32 * 32];
  __shared__ float fb[128];
  __shared__ float c0s[32];
  __shared__ float bes[32];
  int tid = threadIdx.x;
  for (int i = tid; i < 96 * 128; i += 512) {
    int k = i >> 7, col = i & 127;
    wlds[k * 144 + (col >> 5) * 36 + (col & 31)] = Wm2[k * 129 + 1 + col];
  }
  for (int i = tid; i < 96 * 32; i += 512) wc[i] = ws[O2_WC + i];
  for (int i = tid; i < 32 * 32; i += 512) wet[i] = We[(128 + (i >> 5)) * 32 + (i & 31)];
  if (tid < 128) fb[tid] = bm2[1 + tid];
  if (tid < 32) { c0s[tid] = ws[O2_C0 + tid]; bes[tid] = be[tid]; }
  __syncthreads();

  int eg = tid >> 2, q = tid & 3;
  int e = blockIdx.x * 128 + eg;
  const float4* hp4 = (const float4*)(ws + O2_H + (size_t)e * 96);
  float gate = ws[O2_G + e];

  // ---- f-phase: f[32q+j] = gate*(sum_k h[k]*Wm2[k][1+32q+j] + bias) ----
  float f[32];
  #pragma unroll
  for (int j = 0; j < 32; j++) f[j] = 0.f;
  #pragma unroll
  for (int c = 0; c < 6; c++) {
    float4 h0 = hp4[c * 4 + 0], h1 = hp4[c * 4 + 1];
    float4 h2 = hp4[c * 4 + 2], h3 = hp4[c * 4 + 3];
    float hs[16] = {h0.x, h0.y, h0.z, h0.w, h1.x, h1.y, h1.z, h1.w,
                    h2.x, h2.y, h2.z, h2.w, h3.x, h3.y, h3.z, h3.w};
    int kb = c * 16;
    #pragma unroll
    for (int kk = 0; kk < 16; kk++) {
      const float* w = wlds + (kb + kk) * 144 + q * 36;
      accN<32>(hs[kk], w, f);
    }
  }
  #pragma unroll
  for (int j = 0; j < 32; j++) f[j] = gate * (f[j] + fb[32 * q + j]);
  {
    float4* fp = (float4*)(ws + O2_F + (size_t)e * 128 + 32 * q);  // 128B align
    #pragma unroll
    for (int jc = 0; jc < 8; jc++) {
      float4 o;
      o.x = f[jc * 4 + 0]; o.y = f[jc * 4 + 1];
      o.z = f[jc * 4 + 2]; o.w = f[jc * 4 + 3];
      fp[jc] = o;
    }
  }

  // ---- ove-phase: out_ve[8q+j] = gate*(h@Wc + c0) + ve@WeT + be ----
  float ov[8];
  #pragma unroll
  for (int j = 0; j < 8; j++) ov[j] = 0.f;
  #pragma unroll
  for (int c = 0; c < 6; c++) {       // h re-read: L1-hot (just read above)
    float4 h0 = hp4[c * 4 + 0], h1 = hp4[c * 4 + 1];
    float4 h2 = hp4[c * 4 + 2], h3 = hp4[c * 4 + 3];
    float hs[16] = {h0.x, h0.y, h0.z, h0.w, h1.x, h1.y, h1.z, h1.w,
                    h2.x, h2.y, h2.z, h2.w, h3.x, h3.y, h3.z, h3.w};
    int kb = c * 16;
    #pragma unroll
    for (int kk = 0; kk < 16; kk++)
      accN<8>(hs[kk], wc + (kb + kk) * 32 + 8 * q, ov);
  }
  #pragma unroll
  for (int j = 0; j < 8; j++) ov[j] = gate * (ov[j] + c0s[8 * q + j]);
  {
    const float4* v4 = (const float4*)(in_ve + (size_t)e * 32);
    #pragma unroll
    for (int kc = 0; kc < 8; kc++) {
      float4 vq = v4[kc];
      accN<8>(vq.x, wet + (kc * 4 + 0) * 32 + 8 * q, ov);
      accN<8>(vq.y, wet + (kc * 4 + 1) * 32 + 8 * q, ov);
      accN<8>(vq.z, wet + (kc * 4 + 2) * 32 + 8 * q, ov);
      accN<8>(vq.w, wet + (kc * 4 + 3) * 32 + 8 * q, ov);
    }
  }
  #pragma unroll
  for (int j = 0; j < 8; j++) ov[j] += bes[8 * q + j];
  {
    float4* op = (float4*)(out_ve + (size_t)e * 32 + 8 * q);  // 32B-aligned
    float4 o0, o1;
    o0.x = ov[0]; o0.y = ov[1]; o0.z = ov[2]; o0.w = ov[3];
    o1.x = ov[4]; o1.y = ov[5]; o1.z = ov[6]; o1.w = ov[7];
    op[0] = o0; op[1] = o1;
  }
}

// ======== node kernel: CSR gather reductions + node MLP =====================
__global__ __launch_bounds__(256) void gsmp_node_fast(
    const float* __restrict__ in_vc, const float* __restrict__ Wr,
    const float* __restrict__ br, const float* __restrict__ ws,
    float* __restrict__ out_vc)
{
  __shared__ float xs[8][128];
  int g = threadIdx.x >> 5;
  int j = threadIdx.x & 31;
  int n = blockIdx.x * 8 + g;

  const unsigned* off  = (const unsigned*)ws + O2_OFF;
  const unsigned* eidx = (const unsigned*)ws + O2_EIDX;
  const float* fbuf = ws + O2_F;

  unsigned beg = 0, end = 0;
  if (n < N_NODES) { beg = off[n]; end = off[n + 1]; }

  const float INF = __builtin_huge_valf();
  float s1 = 0.f, m4 = 0.f, m2 = -INF, m3 = INF;
  for (unsigned i = beg; i < end; i++) {
    unsigned e = eidx[i];
    const float* __restrict__ fb = fbuf + (size_t)e * 128;
    s1 += fb[j];
    m2 = fmaxf(m2, fb[32 + j]);
    m3 = fminf(m3, fb[64 + j]);
    m4 += fb[96 + j];
  }
  bool has = end > beg;
  if (!has) { m2 = 0.f; m3 = 0.f; }
  m4 *= has ? (1.f / (float)(end - beg)) : 1.f;

  xs[g][0 * 32 + j] = s1;
  xs[g][1 * 32 + j] = m2;
  xs[g][2 * 32 + j] = m3;
  xs[g][3 * 32 + j] = m4;
  __syncthreads();
  if (n >= N_NODES) return;

  float acc = br[j];
  const float* vcn = in_vc + (size_t)n * 32;
  #pragma unroll 8
  for (int k = 0; k < 32; k++)  acc = fmaf(vcn[k], Wr[k * 32 + j], acc);
  const float* xg = xs[g];
  #pragma unroll 8
  for (int k = 0; k < 128; k++) acc = fmaf(xg[k], Wr[(32 + k) * 32 + j], acc);
  out_vc[(size_t)n * 32 + j] = acc;
}

// ====== WS2 fallback edge kernel (round-3 verified, 2188us) =================
#define EB 128
#define HLO 56
#define HHI 40
__global__ __launch_bounds__(EB, 3) void gsmp_edge_fast(
    const float* __restrict__ in_vc, const float* __restrict__ in_ve,
    const int* __restrict__ src, const int* __restrict__ dst,
    const float* __restrict__ Wm1, const float* __restrict__ bm1,
    const float* __restrict__ Wm2, const float* __restrict__ bm2,
    const float* __restrict__ We, const float* __restrict__ be,
    float* __restrict__ ws, float* __restrict__ out_ve)
{
  __shared__ float hlds[EB * HHI];
  int e = blockIdx.x * EB + threadIdx.x;
  bool act = e < N_EDGES;
  int e0 = act ? e : 0;
  int sn = src[e0] * 32;
  int dn = dst[e0] * 32;
  size_t eoff = (size_t)e0 * 32;

  const float* base0 = in_vc + sn;
  const float* base1 = in_vc + dn;
  const float* base2 = in_ve + eoff;
  float* myh = hlds + threadIdx.x * HHI;

  {
    float hh[HHI];
    #pragma unroll
    for (int j = 0; j < HHI; j++) hh[j] = bm1[HLO + j];
    #pragma unroll
    for (int r = 0; r < 3; r++) {
      const float* bp = (r == 0) ? base0 : (r == 1) ? base1 : base2;
      const float4* p4 = (const float4*)bp;
      for (int kc = 0; kc < 8; kc++) {
        float4 xq = p4[kc];
        const float* w = Wm1 + (r * 32 + kc * 4) * 96 + HLO;
        accN<HHI>(xq.x, w + 0 * 96, hh);
        accN<HHI>(xq.y, w + 1 * 96, hh);
        accN<HHI>(xq.z, w + 2 * 96, hh);
        accN<HHI>(xq.w, w + 3 * 96, hh);
      }
    }
    #pragma unroll
    for (int j = 0; j < HHI; j += 4) {
      float4 v;
      v.x = fmaxf(hh[j + 0], 0.f); v.y = fmaxf(hh[j + 1], 0.f);
      v.z = fmaxf(hh[j + 2], 0.f); v.w = fmaxf(hh[j + 3], 0.f);
      *(float4*)(myh + j) = v;
    }
  }

  float hl[HLO];
  #pragma unroll
  for (int j = 0; j < HLO; j++) hl[j] = bm1[j];
  #pragma unroll
  for (int r = 0; r < 3; r++) {
    const float* bp = (r == 0) ? base0 : (r == 1) ? base1 : base2;
    const float4* p4 = (const float4*)bp;
    for (int kc = 0; kc < 8; kc++) {
      float4 xq = p4[kc];
      const float* w = Wm1 + (r * 32 + kc * 4) * 96;
      accN<HLO>(xq.x, w + 0 * 96, hl);
      accN<HLO>(xq.y, w + 1 * 96, hl);
      accN<HLO>(xq.z, w + 2 * 96, hl);
      accN<HLO>(xq.w, w + 3 * 96, hl);
    }
  }
  #pragma unroll
  for (int j = 0; j < HLO; j++) hl[j] = fmaxf(hl[j], 0.f);

  const float4* h4 = (const float4*)myh;

  float y0 = bm2[0];
  #pragma unroll
  for (int k = 0; k < HLO; k++) y0 = fmaf(hl[k], Wm2[k * 129], y0);
  for (int kc = 0; kc < HHI / 4; kc++) {
    float4 hq = h4[kc];
    int k = HLO + kc * 4;
    y0 = fmaf(hq.x, Wm2[(k + 0) * 129], y0);
    y0 = fmaf(hq.y, Wm2[(k + 1) * 129], y0);
    y0 = fmaf(hq.z, Wm2[(k + 2) * 129], y0);
    y0 = fmaf(hq.w, Wm2[(k + 3) * 129], y0);
  }
  float gate = 1.f / (1.f + __expf(-y0));

  float* fbuf = ws + O2_F;

  for (int c = 0; c < 4; c++) {
    float f[32];
    #pragma unroll
    for (int j = 0; j < 32; j++) f[j] = bm2[1 + c * 32 + j];
    #pragma unroll
    for (int k = 0; k < HLO; k++)
      accN<32>(hl[k], Wm2 + k * 129 + 1 + c * 32, f);
    for (int kc = 0; kc < HHI / 4; kc++) {
      float4 hq = h4[kc];
      const float* w = Wm2 + (HLO + kc * 4) * 129 + 1 + c * 32;
      accN<32>(hq.x, w + 0 * 129, f);
      accN<32>(hq.y, w + 1 * 129, f);
      accN<32>(hq.z, w + 2 * 129, f);
      accN<32>(hq.w, w + 3 * 129, f);
    }
    #pragma unroll
    for (int j = 0; j < 32; j++) f[j] *= gate;
    if (act) {
      float4* fp = (float4*)(fbuf + (size_t)e * 128 + c * 32);
      #pragma unroll
      for (int jc = 0; jc < 8; jc++) {
        float4 o;
        o.x = f[jc * 4 + 0]; o.y = f[jc * 4 + 1];
        o.z = f[jc * 4 + 2]; o.w = f[jc * 4 + 3];
        fp[jc] = o;
      }
    }
  }

  const float* Wc = ws + O2_WC;
  const float* c0 = ws + O2_C0;
  float ove[32];
  #pragma unroll
  for (int j = 0; j < 32; j++) ove[j] = 0.f;
  #pragma unroll
  for (int k = 0; k < HLO; k++)
    accN<32>(hl[k], Wc + k * 32, ove);
  for (int kc = 0; kc < HHI / 4; kc++) {
    float4 hq = h4[kc];
    const float* w = Wc + (HLO + kc * 4) * 32;
    accN<32>(hq.x, w + 0 * 32, ove);
    accN<32>(hq.y, w + 1 * 32, ove);
    accN<32>(hq.z, w + 2 * 32, ove);
    accN<32>(hq.w, w + 3 * 32, ove);
  }
  #pragma unroll
  for (int j = 0; j < 32; j++) ove[j] = fmaf(gate, ove[j] + c0[j], be[j]);
  {
    const float4* v4 = (const float4*)base2;
    for (int kc = 0; kc < 8; kc++) {
      float4 vq = v4[kc];
      const float* w = We + (128 + kc * 4) * 32;
      accN<32>(vq.x, w + 0 * 32, ove);
      accN<32>(vq.y, w + 1 * 32, ove);
      accN<32>(vq.z, w + 2 * 32, ove);
      accN<32>(vq.w, w + 3 * 32, ove);
    }
  }
  if (act) {
    float4* op = (float4*)(out_ve + eoff);
    #pragma unroll
    for (int jc = 0; jc < 8; jc++) {
      float4 o;
      o.x = ove[jc * 4 + 0]; o.y = ove[jc * 4 + 1];
      o.z = ove[jc * 4 + 2]; o.w = ove[jc * 4 + 3];
      op[jc] = o;
    }
  }
}

// ===================== legacy atomic-scatter kernels ========================
__global__ __launch_bounds__(EB) void gsmp_edge_kernel(
    const float* __restrict__ in_vc, const float* __restrict__ in_ve,
    const int* __restrict__ src, const int* __restrict__ dst,
    const float* __restrict__ Wm1, const float* __restrict__ bm1,
    const float* __restrict__ Wm2, const float* __restrict__ bm2,
    const float* __restrict__ We, const float* __restrict__ be,
    float* __restrict__ ws, float* __restrict__ out_ve)
{
  __shared__ float hlds[EB * 100];
  int e = blockIdx.x * EB + threadIdx.x;
  bool act = e < N_EDGES;
  int e0 = act ? e : 0;
  int sn = src[e0] * 32;
  int dn = dst[e0] * 32;
  size_t eoff = (size_t)e0 * 32;

  float h[96];
  #pragma unroll
  for (int j = 0; j < 96; j++) h[j] = bm1[j];

  const float* base0 = in_vc + sn;
  const float* base1 = in_vc + dn;
  const float* base2 = in_ve + eoff;
  #pragma unroll
  for (int r = 0; r < 3; r++) {
    const float* bp = (r == 0) ? base0 : (r == 1) ? base1 : base2;
    const float4* p4 = (const float4*)bp;
    for (int kc = 0; kc < 8; kc++) {
      float4 xq = p4[kc];
      const float* w = Wm1 + (r * 32 + kc * 4) * 96;
      accN<96>(xq.x, w + 0 * 96, h);
      accN<96>(xq.y, w + 1 * 96, h);
      accN<96>(xq.z, w + 2 * 96, h);
      accN<96>(xq.w, w + 3 * 96, h);
    }
  }
  float* myh = hlds + threadIdx.x * 100;
  #pragma unroll
  for (int j = 0; j < 96; j += 4) {
    float4 v;
    v.x = fmaxf(h[j + 0], 0.f); v.y = fmaxf(h[j + 1], 0.f);
    v.z = fmaxf(h[j + 2], 0.f); v.w = fmaxf(h[j + 3], 0.f);
    *(float4*)(myh + j) = v;
  }

  const float4* h4 = (const float4*)myh;
  float y0 = bm2[0];
  for (int kc = 0; kc < 24; kc++) {
    float4 hq = h4[kc];
    int k = kc * 4;
    y0 = fmaf(hq.x, Wm2[(k + 0) * 129], y0);
    y0 = fmaf(hq.y, Wm2[(k + 1) * 129], y0);
    y0 = fmaf(hq.z, Wm2[(k + 2) * 129], y0);
    y0 = fmaf(hq.w, Wm2[(k + 3) * 129], y0);
  }
  float gate = 1.f / (1.f + __expf(-y0));

  float* s1  = ws + O_S1;
  float* m4s = ws + O_M4S;
  unsigned* m2k = (unsigned*)ws + O_M2K;
  unsigned* m3k = (unsigned*)ws + O_M3K;
  unsigned* deg = (unsigned*)ws + O_DEG;

  for (int c = 0; c < 4; c++) {
    float f[32];
    #pragma unroll
    for (int j = 0; j < 32; j++) f[j] = bm2[1 + c * 32 + j];
    for (int kc = 0; kc < 24; kc++) {
      float4 hq = h4[kc];
      const float* w = Wm2 + (kc * 4) * 129 + 1 + c * 32;
      accN<32>(hq.x, w + 0 * 129, f);
      accN<32>(hq.y, w + 1 * 129, f);
      accN<32>(hq.z, w + 2 * 129, f);
      accN<32>(hq.w, w + 3 * 129, f);
    }
    #pragma unroll
    for (int j = 0; j < 32; j++) f[j] *= gate;
    if (act) {
      if (c == 0) {
        #pragma unroll
        for (int j = 0; j < 32; j++) atomicAdd(&s1[dn + j], f[j]);
      } else if (c == 1) {
        #pragma unroll
        for (int j = 0; j < 32; j++) atomicMax(&m2k[dn + j], fkey(f[j]));
      } else if (c == 2) {
        #pragma unroll
        for (int j = 0; j < 32; j++) atomicMin(&m3k[dn + j], fkey(f[j]));
      } else {
        #pragma unroll
        for (int j = 0; j < 32; j++) atomicAdd(&m4s[dn + j], f[j]);
      }
    }
  }
  if (act) atomicAdd(&deg[dn >> 5], 1u);

  const float* Wc = ws + O_WC;
  const float* c0 = ws + O_C0;
  float ove[32];
  #pragma unroll
  for (int j = 0; j < 32; j++) ove[j] = 0.f;
  for (int kc = 0; kc < 24; kc++) {
    float4 hq = h4[kc];
    const float* w = Wc + (kc * 4) * 32;
    accN<32>(hq.x, w + 0 * 32, ove);
    accN<32>(hq.y, w + 1 * 32, ove);
    accN<32>(hq.z, w + 2 * 32, ove);
    accN<32>(hq.w, w + 3 * 32, ove);
  }
  #pragma unroll
  for (int j = 0; j < 32; j++) ove[j] = fmaf(gate, ove[j] + c0[j], be[j]);
  {
    const float4* v4 = (const float4*)base2;
    for (int kc = 0; kc < 8; kc++) {
      float4 vq = v4[kc];
      const float* w = We + (128 + kc * 4) * 32;
      accN<32>(vq.x, w + 0 * 32, ove);
      accN<32>(vq.y, w + 1 * 32, ove);
      accN<32>(vq.z, w + 2 * 32, ove);
      accN<32>(vq.w, w + 3 * 32, ove);
    }
  }
  if (act) {
    float4* op = (float4*)(out_ve + eoff);
    #pragma unroll
    for (int jc = 0; jc < 8; jc++) {
      float4 o;
      o.x = ove[jc * 4 + 0]; o.y = ove[jc * 4 + 1];
      o.z = ove[jc * 4 + 2]; o.w = ove[jc * 4 + 3];
      op[jc] = o;
    }
  }
}

__global__ __launch_bounds__(256) void gsmp_node_kernel(
    const float* __restrict__ in_vc, const float* __restrict__ Wr,
    const float* __restrict__ br, const float* __restrict__ ws,
    float* __restrict__ out_vc)
{
  int n = blockIdx.x * 256 + threadIdx.x;
  if (n >= N_NODES) return;
  const float* s1  = ws + O_S1;
  const float* m4s = ws + O_M4S;
  const unsigned* m2k = (const unsigned*)ws + O_M2K;
  const unsigned* m3k = (const unsigned*)ws + O_M3K;
  const unsigned* deg = (const unsigned*)ws + O_DEG;

  unsigned d = deg[n];
  bool has = d > 0;
  float invd = 1.f / (float)(has ? d : 1u);
  int nb = n * 32;

  float acc[32];
  #pragma unroll
  for (int j = 0; j < 32; j++) acc[j] = br[j];

  for (int k = 0; k < 32; k++) accN<32>(in_vc[nb + k],                 Wr + (0   + k) * 32, acc);
  for (int k = 0; k < 32; k++) accN<32>(s1[nb + k],                    Wr + (32  + k) * 32, acc);
  for (int k = 0; k < 32; k++) accN<32>(has ? fdec(m2k[nb + k]) : 0.f, Wr + (64  + k) * 32, acc);
  for (int k = 0; k < 32; k++) accN<32>(has ? fdec(m3k[nb + k]) : 0.f, Wr + (96  + k) * 32, acc);
  for (int k = 0; k < 32; k++) accN<32>(m4s[nb + k] * invd,            Wr + (128 + k) * 32, acc);

  float4* op = (float4*)(out_vc + (size_t)nb);
  #pragma unroll
  for (int jc = 0; jc < 8; jc++) {
    float4 o;
    o.x = acc[jc * 4 + 0]; o.y = acc[jc * 4 + 1];
    o.z = acc[jc * 4 + 2]; o.w = acc[jc * 4 + 3];
    op[jc] = o;
  }
}

extern "C" void kernel_launch(void* const* d_in, const int* in_sizes, int n_in,
                              void* d_out, int out_size, void* d_ws, size_t ws_size,
                              hipStream_t stream) {
  const float* in_vc = (const float*)d_in[0];
  const float* in_ve = (const float*)d_in[1];
  const int*   src   = (const int*)d_in[2];
  const int*   dst   = (const int*)d_in[3];
  const float* Wm1   = (const float*)d_in[4];
  const float* bm1   = (const float*)d_in[5];
  const float* Wm2   = (const float*)d_in[6];
  const float* bm2   = (const float*)d_in[7];
  const float* Wr    = (const float*)d_in[8];
  const float* br    = (const float*)d_in[9];
  const float* We    = (const float*)d_in[10];
  const float* be    = (const float*)d_in[11];

  float* ws     = (float*)d_ws;
  float* out_vc = (float*)d_out;
  float* out_ve = out_vc + (size_t)N_NODES * 32;

  if (ws_size >= WS3_BYTES) {
    // -------- split pipeline: LDS-resident weights, no SGPR streaming ------
    hipMemsetAsync(ws + O2_DEG, 0, (size_t)N_NODES * 4, stream);
    gsmp_make_wc<<<13, 256, 0, stream>>>(Wm2, bm2, We, ws + O2_WC, ws + O2_C0);
    gsmp_hist<<<(N_EDGES + 255) / 256, 256, 0, stream>>>(dst, (unsigned*)ws + O2_DEG);
    gsmp_scan<<<1, 1024, 0, stream>>>(ws);
    gsmp_fill<<<(N_EDGES + 255) / 256, 256, 0, stream>>>(dst, ws);
    gsmp_edge_h<<<N_EDGES / 128, 512, 0, stream>>>(
        in_vc, in_ve, src, dst, Wm1, bm1, Wm2, bm2, ws);
    gsmp_edge_f<<<N_EDGES / 128, 512, 0, stream>>>(
        in_ve, Wm2, bm2, We, be, ws, out_ve);
    gsmp_node_fast<<<(N_NODES + 7) / 8, 256, 0, stream>>>(in_vc, Wr, br, ws, out_vc);
  } else if (ws_size >= WS2_BYTES) {
    // -------- round-3 verified CSR path ------------------------------------
    hipMemsetAsync(ws + O2_DEG, 0, (size_t)N_NODES * 4, stream);
    gsmp_make_wc<<<13, 256, 0, stream>>>(Wm2, bm2, We, ws + O2_WC, ws + O2_C0);
    gsmp_hist<<<(N_EDGES + 255) / 256, 256, 0, stream>>>(dst, (unsigned*)ws + O2_DEG);
    gsmp_scan<<<1, 1024, 0, stream>>>(ws);
    gsmp_fill<<<(N_EDGES + 255) / 256, 256, 0, stream>>>(dst, ws);
    gsmp_edge_fast<<<N_EDGES / EB, EB, 0, stream>>>(
        in_vc, in_ve, src, dst, Wm1, bm1, Wm2, bm2, We, be, ws, out_ve);
    gsmp_node_fast<<<(N_NODES + 7) / 8, 256, 0, stream>>>(in_vc, Wr, br, ws, out_vc);
  } else if (ws_size >= WS_BYTES) {
    // -------- legacy atomic-scatter path -----------------------------------
    hipMemsetAsync(ws + O_S1, 0, (size_t)(O_M3K - O_S1) * 4, stream);
    hipMemsetAsync(ws + O_M3K, 0xFF, (size_t)(N_NODES * 32) * 4, stream);
    gsmp_make_wc<<<13, 256, 0, stream>>>(Wm2, bm2, We, ws + O_WC, ws + O_C0);
    gsmp_edge_kernel<<<N_EDGES / EB, EB, 0, stream>>>(
        in_vc, in_ve, src, dst, Wm1, bm1, Wm2, bm2, We, be, ws, out_ve);
    gsmp_node_kernel<<<(N_NODES + 255) / 256, 256, 0, stream>>>(
        in_vc, Wr, br, ws, out_vc);
  }
  // else: workspace too small — bail cleanly (shows as absmax failure).
}